// Round 12
// baseline (2744.698 us; speedup 1.0000x reference)
//
#include <hip/hip_runtime.h>

#define BB 8
#define NN 8192
#define KK 6
#define DD 256
#define LL 5
#define NE (BB*NN*KK)       // 393216
#define PLANE (NN*DD)       // 2097152 elems per batch
#define INV6 (1.0f/6.000001f)

typedef unsigned short u16;
typedef __attribute__((ext_vector_type(8))) _Float16 h8;
typedef __attribute__((ext_vector_type(8))) unsigned short us8;
typedef __attribute__((ext_vector_type(4))) float f32x4;

__device__ __forceinline__ u16 f2h(float f){
  union { _Float16 h; u16 u; } c; c.h = (_Float16)f; return c.u;
}
__device__ __forceinline__ float h2f(u16 u){
  union { _Float16 h; u16 u; } c; c.u = u; return (float)c.h;
}

// async global->LDS 16B copy: LDS dest must be wave-uniform base + lane*16
__device__ __forceinline__ void ldscp(const u16* g, u16* l){
  __builtin_amdgcn_global_load_lds(
      (const __attribute__((address_space(1))) void*)g,
      (__attribute__((address_space(3))) void*)l, 16, 0, 0);
}

// ---------------- CSR build ----------------
__global__ void k_count(const int* __restrict__ knn, int* __restrict__ off){
  int e = blockIdx.x*256 + threadIdx.x;
  if(e >= NE) return;
  int b = e / (NN*KK);
  int j = knn[e];
  atomicAdd(&off[b*(NN+1) + 1 + j], 1);
}

__global__ __launch_bounds__(1024) void k_scan(int* __restrict__ offAll){
  __shared__ int lds[1024];
  __shared__ int carry_s;
  int* off = offAll + blockIdx.x*(NN+1);
  const int len = NN+1;
  int t = threadIdx.x;
  if(t==0) carry_s = 0;
  __syncthreads();
  for(int base=0; base<len; base+=1024){
    int x = (base+t < len) ? off[base+t] : 0;
    lds[t] = x; __syncthreads();
    for(int s=1; s<1024; s<<=1){
      int v = (t>=s) ? lds[t-s] : 0;
      __syncthreads();
      lds[t] += v;
      __syncthreads();
    }
    int incl = lds[t];
    int carry = carry_s;
    __syncthreads();
    if(base+t < len) off[base+t] = incl + carry;
    if(t==1023) carry_s = carry + incl;
    __syncthreads();
  }
}

__global__ void k_fill(const int* __restrict__ knn, int* __restrict__ cursor, int* __restrict__ srcE){
  int e = blockIdx.x*256 + threadIdx.x;
  if(e >= NE) return;
  int b = e / (NN*KK);
  int n = (e % (NN*KK)) / KK;
  int j = knn[e];
  int pos = atomicAdd(&cursor[b*(NN+1) + j], 1);
  srcE[(long)b*NN*KK + pos] = n;
}

// ---- weight prep: W fp32 [L][256][N] -> Wt hi/lo fp16 [L][2][N][256] ----
__global__ __launch_bounds__(256) void k_prepw(const float* __restrict__ W, u16* __restrict__ Wt, int N){
  int n = blockIdx.x, l = blockIdx.y, k = threadIdx.x;
  float x = W[((long)l*256 + k)*N + n];
  u16 hb = f2h(x);
  Wt[(((long)l*2 + 0)*N + n)*256 + k] = hb;
  Wt[(((long)l*2 + 1)*N + n)*256 + k] = f2h(x - h2f(hb));
}

// ---------------- embed ----------------
__global__ __launch_bounds__(256) void k_embed(const float* __restrict__ x, const float* __restrict__ ew,
                        const float* __restrict__ eb, float* __restrict__ h){
  int g = blockIdx.x, z = blockIdx.y, d = threadIdx.x;
  const float* xp = x + ((long)z*NN + g)*3;
  h[(long)z*PLANE + (long)g*DD + d] = xp[0]*ew[0*DD+d] + xp[1]*ew[1*DD+d] + xp[2]*ew[2*DD+d] + eb[d];
}

// ---------------- layernorm fp32 -> fp16 single plane ----------------
__global__ __launch_bounds__(256) void k_ln(const float* __restrict__ h, const float* __restrict__ g,
                     const float* __restrict__ bia, u16* __restrict__ out){
  long z = blockIdx.y;
  int row = blockIdx.x*4 + (threadIdx.x >> 6);
  int lane = threadIdx.x & 63;
  const float4 x = *(const float4*)(h + z*PLANE + (long)row*DD + lane*4);
  float s  = x.x + x.y + x.z + x.w;
  float s2 = x.x*x.x + x.y*x.y + x.z*x.z + x.w*x.w;
  for(int o=1;o<64;o<<=1){ s += __shfl_xor(s,o); s2 += __shfl_xor(s2,o); }
  float m = s*(1.0f/256.0f);
  float var = s2*(1.0f/256.0f) - m*m;
  float r = rsqrtf(var + 1e-5f);
  const float4 gu = *(const float4*)(g + lane*4);
  const float4 bu = *(const float4*)(bia + lane*4);
  ushort4 o4;
  o4.x = f2h((x.x-m)*r*gu.x + bu.x);
  o4.y = f2h((x.y-m)*r*gu.y + bu.y);
  o4.z = f2h((x.z-m)*r*gu.z + bu.z);
  o4.w = f2h((x.w-m)*r*gu.w + bu.w);
  *(ushort4*)(out + z*PLANE + (long)row*DD + lane*4) = o4;
}

// ---------------- fp16 MFMA GEMM (qkv 128-tile sections + w2t 64-tile legacy) ----------------
template<int BM,int BN,bool ASPLIT,bool BF32,bool BSPLIT>
__global__ __launch_bounds__(256) void k_mgemm(
    const u16* __restrict__ A, long aStride, long aLoOff, int K, int kSplit,
    const void* __restrict__ Bv, long bStride, long bLoOff,
    const float* __restrict__ rowscale, long rsStride,
    const float* __restrict__ bias,
    u16* __restrict__ o0, u16* __restrict__ o1, u16* __restrict__ o2,
    long oStride, int reluMask, long oLoOff,
    float* __restrict__ accOut, long hStride)
{
  constexpr int WM = BM/2, WN = BN/2, MT = WM/16, NT = WN/16;
  constexpr int STG = BM*32*(ASPLIT?2:1) + BN*32*(BSPLIT?2:1);
  constexpr int EPI = (BM==128) ? 32*132*2 : 0;
  constexpr int SM  = (STG > EPI) ? STG : EPI;
  __shared__ __align__(16) u16 smem[SM];
  u16* Ahi = smem;
  u16* Alo = smem + BM*32;
  u16* Bhi = smem + BM*32*(ASPLIT?2:1);
  u16* Blo = Bhi + BN*32;
  float* epi = (float*)smem;

  const int t = threadIdx.x;
  const int nz = blockIdx.z;
  const long z = nz / kSplit;
  const int chunk = nz % kSplit;
  const int kLen = K / kSplit, kLo = chunk * kLen;
  const int rowTile = blockIdx.x*BM, colTile = blockIdx.y*BN;
  const int l = t & 63, w = t >> 6;
  const int wr = w >> 1, wc = w & 1;
  const int lm = l & 15, kq = l >> 4;

  f32x4 acc[MT][NT];
  #pragma unroll
  for(int mt=0;mt<MT;mt++)
    #pragma unroll
    for(int nt=0;nt<NT;nt++) acc[mt][nt] = (f32x4){0.f,0.f,0.f,0.f};

  for(int k0=kLo; k0<kLo+kLen; k0+=32){
    __syncthreads();
    {
      constexpr int NCH = BM/64;
      #pragma unroll
      for(int li=0; li<NCH; li++){
        int f = li*256 + t;
        int row = f>>2, c = (f&3)*8;
        const u16* gp = A + z*aStride + (long)(rowTile+row)*K + k0 + c;
        ldscp(gp, &Ahi[f*8]);
        if constexpr (ASPLIT) ldscp(gp + aLoOff, &Alo[f*8]);
      }
    }
    if constexpr (BF32){
      constexpr int NCH = BN/64;
      #pragma unroll
      for(int li=0; li<NCH; li++){
        int f = li*256 + t;
        int row = f>>2, c = (f&3)*8;
        const float* src = (const float*)Bv + z*bStride + (long)(colTile+row)*K + k0 + c;
        float4 v0 = ((const float4*)src)[0], v1 = ((const float4*)src)[1];
        us8 hv;
        hv[0]=f2h(v0.x); hv[1]=f2h(v0.y); hv[2]=f2h(v0.z); hv[3]=f2h(v0.w);
        hv[4]=f2h(v1.x); hv[5]=f2h(v1.y); hv[6]=f2h(v1.z); hv[7]=f2h(v1.w);
        *(us8*)&Bhi[f*8] = hv;
      }
    } else {
      constexpr int NCH = BN/64;
      #pragma unroll
      for(int li=0; li<NCH; li++){
        int f = li*256 + t;
        int row = f>>2, c = (f&3)*8;
        const u16* gp = (const u16*)Bv + z*bStride + (long)(colTile+row)*K + k0 + c;
        ldscp(gp, &Bhi[f*8]);
        if constexpr (BSPLIT) ldscp(gp + bLoOff, &Blo[f*8]);
      }
    }
    __syncthreads();
    h8 ah[MT], al[MT], bh[NT], bl[NT];
    #pragma unroll
    for(int mt=0;mt<MT;mt++){
      int idx = (wr*WM + mt*16 + lm)*32 + kq*8;
      ah[mt] = *(const h8*)&Ahi[idx];
      if constexpr (ASPLIT) al[mt] = *(const h8*)&Alo[idx];
    }
    #pragma unroll
    for(int nt=0;nt<NT;nt++){
      int idx = (wc*WN + nt*16 + lm)*32 + kq*8;
      bh[nt] = *(const h8*)&Bhi[idx];
      if constexpr (BSPLIT) bl[nt] = *(const h8*)&Blo[idx];
    }
    #pragma unroll
    for(int mt=0;mt<MT;mt++)
      #pragma unroll
      for(int nt=0;nt<NT;nt++){
        acc[mt][nt] = __builtin_amdgcn_mfma_f32_16x16x32_f16(ah[mt], bh[nt], acc[mt][nt], 0, 0, 0);
        if constexpr (BSPLIT)
          acc[mt][nt] = __builtin_amdgcn_mfma_f32_16x16x32_f16(ah[mt], bl[nt], acc[mt][nt], 0, 0, 0);
        if constexpr (ASPLIT)
          acc[mt][nt] = __builtin_amdgcn_mfma_f32_16x16x32_f16(al[mt], bh[nt], acc[mt][nt], 0, 0, 0);
      }
  }

  if constexpr (BM == 128){
    const int sec = colTile >> 8;
    u16* osec = (sec==0) ? o0 : ((sec==1) ? o1 : o2);
    const bool relu = (reluMask >> sec) & 1;
    #pragma unroll
    for(int mt=0;mt<MT;mt++){
      __syncthreads();
      #pragma unroll
      for(int r=0;r<4;r++){
        int gm = rowTile + wr*64 + mt*16 + kq*4 + r;
        float sc = rowscale ? rowscale[z*rsStride + gm] : 1.0f;
        int rl = wr*16 + kq*4 + r;
        #pragma unroll
        for(int nt=0;nt<NT;nt++)
          epi[rl*132 + wc*64 + nt*16 + lm] = acc[mt][nt][r]*sc;
      }
      __syncthreads();
      #pragma unroll
      for(int ss=0;ss<2;ss++){
        int s = ss*256 + t;
        int rl = s >> 4, sc8 = (s & 15)*8;
        int gm2 = rowTile + (rl>>4)*64 + mt*16 + (rl & 15);
        float v[8];
        #pragma unroll
        for(int j=0;j<8;j++) v[j] = epi[rl*132 + sc8 + j];
        if(bias){
          const float* bp = bias + colTile + sc8;
          #pragma unroll
          for(int j=0;j<8;j++) v[j] += bp[j];
        }
        if(accOut){
          float* hp = accOut + z*hStride + (long)gm2*256 + colTile + sc8;
          float4 h0 = ((float4*)hp)[0], h1 = ((float4*)hp)[1];
          h0.x += v[0]; h0.y += v[1]; h0.z += v[2]; h0.w += v[3];
          h1.x += v[4]; h1.y += v[5]; h1.z += v[6]; h1.w += v[7];
          ((float4*)hp)[0] = h0; ((float4*)hp)[1] = h1;
        } else {
          us8 o8;
          #pragma unroll
          for(int j=0;j<8;j++){
            float vv = v[j];
            if(relu) vv = fmaxf(vv, 0.f) + 1e-6f;
            o8[j] = f2h(vv);
          }
          *(us8*)(osec + z*oStride + (long)gm2*256 + ((colTile + sc8) & 255)) = o8;
        }
      }
    }
  } else {
    #pragma unroll
    for(int mt=0;mt<MT;mt++){
      #pragma unroll
      for(int r=0;r<4;r++){
        int gm = rowTile + wr*WM + mt*16 + kq*4 + r;
        float sc = rowscale ? rowscale[z*rsStride + gm] : 1.0f;
        if(accOut){
          float* hp = accOut + z*hStride + (long)gm*256;
          if(kSplit > 1){
            #pragma unroll
            for(int nt=0;nt<NT;nt++){
              int gc = colTile + wc*WN + nt*16 + lm;
              atomicAdd(&hp[gc], acc[mt][nt][r]);
            }
          } else {
            #pragma unroll
            for(int nt=0;nt<NT;nt++){
              int gc = colTile + wc*WN + nt*16 + lm;
              hp[gc] += acc[mt][nt][r]*sc + (bias ? bias[gc] : 0.f);
            }
          }
        } else {
          #pragma unroll
          for(int nt=0;nt<NT;nt++){
            int gc = colTile + wc*WN + nt*16 + lm;
            int sec = gc >> 8;
            u16* o = (sec==0) ? o0 : ((sec==1) ? o1 : o2);
            float val = acc[mt][nt][r]*sc + (bias ? bias[gc] : 0.f);
            if((reluMask >> sec) & 1) val = fmaxf(val, 0.f) + 1e-6f;
            if(sec==0 && oLoOff){
              u16* oo = o0 + 2*z*oStride + (long)gm*256 + (gc & 255);
              u16 hb = f2h(val);
              oo[0] = hb;
              oo[oLoOff] = f2h(val - h2f(hb));
            } else {
              o[z*oStride + (long)gm*256 + (gc & 255)] = f2h(val);
            }
          }
        }
      }
    }
  }
}

// ------------- fused k+v spmm gather (fp16 planes, fp32 accum) -------------
template<int MODE>
__global__ __launch_bounds__(256) void k_spmm2(
    const u16* __restrict__ kin, const u16* __restrict__ vin,
    const int* __restrict__ offB, const int* __restrict__ srcB,
    u16* __restrict__ kout, u16* __restrict__ vout,
    const u16* __restrict__ q, float* __restrict__ rs){
  long z = blockIdx.x;
  const u16* kp = kin + z*PLANE;
  const u16* vp = vin + z*PLANE;
  const int* off = offB + z*(NN+1);
  const int* sE  = srcB + z*(long)NN*KK;
  int row = blockIdx.y*8 + (threadIdx.x >> 5);
  int l32 = threadIdx.x & 31;
  int d8 = l32*8;
  int s0 = off[row], s1 = off[row+1];
  float ak[8], av[8];
  #pragma unroll
  for(int j=0;j<8;j++){ ak[j]=0.f; av[j]=0.f; }
  int e = s0;
  for(; e+1 < s1; e += 2){
    int n0 = sE[e], n1 = sE[e+1];
    us8 k0 = *(const us8*)(kp + (long)n0*DD + d8);
    us8 k1 = *(const us8*)(kp + (long)n1*DD + d8);
    us8 v0 = *(const us8*)(vp + (long)n0*DD + d8);
    us8 v1 = *(const us8*)(vp + (long)n1*DD + d8);
    #pragma unroll
    for(int j=0;j<8;j++){
      ak[j] += h2f(k0[j]) + h2f(k1[j]);
      av[j] += h2f(v0[j]) + h2f(v1[j]);
    }
  }
  if(e < s1){
    int n0 = sE[e];
    us8 k0 = *(const us8*)(kp + (long)n0*DD + d8);
    us8 v0 = *(const us8*)(vp + (long)n0*DD + d8);
    #pragma unroll
    for(int j=0;j<8;j++){ ak[j] += h2f(k0[j]); av[j] += h2f(v0[j]); }
  }
  if constexpr (MODE == 0){
    us8 ok, ov;
    #pragma unroll
    for(int j=0;j<8;j++){ ok[j] = f2h(ak[j]*INV6); ov[j] = f2h(av[j]*INV6); }
    *(us8*)(kout + z*PLANE + (long)row*DD + d8) = ok;
    *(us8*)(vout + z*PLANE + (long)row*DD + d8) = ov;
  } else {
    us8 ov;
    #pragma unroll
    for(int j=0;j<8;j++) ov[j] = f2h(av[j]*INV6);
    *(us8*)(vout + z*PLANE + (long)row*DD + d8) = ov;
    us8 qv = *(const us8*)(q + z*PLANE + (long)row*DD + d8);
    float s = 0.f;
    #pragma unroll
    for(int j=0;j<8;j++) s += h2f(qv[j]) * ak[j];
    for(int o=1;o<32;o<<=1) s += __shfl_xor(s,o);
    if(l32==0) rs[z*NN + row] = s*INV6;
  }
}

// ---------------- z = 1/(q . ksum + 1e-6), q fp16 ----------------
__global__ __launch_bounds__(256) void k_zcalc(const u16* __restrict__ q, const float* __restrict__ ksum,
                        float* __restrict__ rs){
  long z = blockIdx.y;
  int row = blockIdx.x*4 + (threadIdx.x >> 6);
  int lane = threadIdx.x & 63;
  ushort4 qv = *(const ushort4*)(q + z*PLANE + (long)row*DD + lane*4);
  const float4 c = *(const float4*)(ksum + z*DD + lane*4);
  float s = h2f(qv.x)*c.x + h2f(qv.y)*c.y + h2f(qv.z)*c.z + h2f(qv.w)*c.w;
  for(int o=1;o<64;o<<=1) s += __shfl_xor(s,o);
  if(lane==0) rs[z*NN + row] = 1.0f / (s + 1e-6f);
}

// ---- kv[d][e] = sum_n k[n][d] v[n][e] from row-major planes (in-LDS transpose, split-K=8) ----
__global__ __launch_bounds__(256) void k_kv(const u16* __restrict__ kAll, const u16* __restrict__ vAll,
                                            float* __restrict__ kvf){
  __shared__ u16 Kt[64*40];
  __shared__ u16 Vt[64*40];
  int nz = blockIdx.z;
  long z = nz >> 3;
  int chunk = nz & 7;
  int dT = blockIdx.x*64, eT = blockIdx.y*64;
  const u16* kp = kAll + z*PLANE;
  const u16* vp = vAll + z*PLANE;
  const int t = threadIdx.x;
  const int l = t & 63, w = t >> 6;
  const int wr = w >> 1, wc = w & 1;
  const int lm = l & 15, kq = l >> 4;
  const int nrow = t >> 3, c8 = (t & 7)*8;

  f32x4 acc[2][2];
  #pragma unroll
  for(int mt=0;mt<2;mt++)
    #pragma unroll
    for(int nt=0;nt<2;nt++) acc[mt][nt] = (f32x4){0.f,0.f,0.f,0.f};

  int n0 = chunk*1024;
  for(int nn=n0; nn<n0+1024; nn+=32){
    us8 kk = *(const us8*)(kp + (long)(nn+nrow)*DD + dT + c8);
    us8 vv = *(const us8*)(vp + (long)(nn+nrow)*DD + eT + c8);
    __syncthreads();
    #pragma unroll
    for(int j=0;j<8;j++){
      Kt[(c8+j)*40 + nrow] = kk[j];
      Vt[(c8+j)*40 + nrow] = vv[j];
    }
    __syncthreads();
    h8 af[2], bf[2];
    #pragma unroll
    for(int mt=0;mt<2;mt++) af[mt] = *(const h8*)&Kt[(wr*32 + mt*16 + lm)*40 + kq*8];
    #pragma unroll
    for(int nt=0;nt<2;nt++) bf[nt] = *(const h8*)&Vt[(wc*32 + nt*16 + lm)*40 + kq*8];
    #pragma unroll
    for(int mt=0;mt<2;mt++)
      #pragma unroll
      for(int nt=0;nt<2;nt++)
        acc[mt][nt] = __builtin_amdgcn_mfma_f32_16x16x32_f16(af[mt], bf[nt], acc[mt][nt], 0, 0, 0);
  }
  #pragma unroll
  for(int mt=0;mt<2;mt++)
    #pragma unroll
    for(int r=0;r<4;r++){
      int gd = dT + wr*32 + mt*16 + kq*4 + r;
      #pragma unroll
      for(int nt=0;nt<2;nt++){
        int ge = eT + wc*32 + nt*16 + lm;
        atomicAdd(&kvf[z*DD*DD + (long)gd*256 + ge], acc[mt][nt][r]);
      }
    }
}

// ---- ksum[d] = sum_n k[n][d], row-major k fp16, atomic over 16 chunks ----
__global__ __launch_bounds__(256) void k_ksum2(const u16* __restrict__ kAll, float* __restrict__ ksum){
  long z = blockIdx.y;
  int c = blockIdx.x;
  const u16* p = kAll + z*PLANE + ((long)c*512)*DD;
  int d = threadIdx.x;
  float s = 0.f;
  for(int i=0;i<512;i++) s += h2f(p[(long)i*DD + d]);
  atomicAdd(&ksum[z*DD + d], s);
}

// ---------------- head ----------------
__global__ __launch_bounds__(256) void k_head(const float* __restrict__ h, const float* __restrict__ hw,
                       const float* __restrict__ hb, float* __restrict__ out){
  long z = blockIdx.y;
  int row = blockIdx.x*4 + (threadIdx.x >> 6);
  int lane = threadIdx.x & 63;
  const float4 x = *(const float4*)(h + z*PLANE + (long)row*DD + lane*4);
  int d0 = lane*4;
  float a0 = x.x*hw[(d0+0)*3+0] + x.y*hw[(d0+1)*3+0] + x.z*hw[(d0+2)*3+0] + x.w*hw[(d0+3)*3+0];
  float a1 = x.x*hw[(d0+0)*3+1] + x.y*hw[(d0+1)*3+1] + x.z*hw[(d0+2)*3+1] + x.w*hw[(d0+3)*3+1];
  float a2 = x.x*hw[(d0+0)*3+2] + x.y*hw[(d0+1)*3+2] + x.z*hw[(d0+2)*3+2] + x.w*hw[(d0+3)*3+2];
  for(int o=1;o<64;o<<=1){
    a0 += __shfl_xor(a0,o); a1 += __shfl_xor(a1,o); a2 += __shfl_xor(a2,o);
  }
  if(lane==0){
    float* op = out + (z*NN + row)*3;
    op[0] = a0 + hb[0];
    op[1] = a1 + hb[1];
    op[2] = a2 + hb[2];
  }
}

struct Carve {
  float *h; u16 *L,*Q,*Bp,*Cp,*T;
  float *kvf; u16 *w2t;
  float *ksum,*rs;
  int *off,*cursor,*srcE;
  u16 *wt_gqkv,*wt_aqkv,*wt_gout,*wt_aout;
  size_t total;
};

static Carve carve(char* base, int C){
  Carve c;
  size_t cur = 0;
  auto bump = [&](size_t bytes)->char*{
    char* p = base ? base + cur : (char*)0;
    cur += (bytes + 255) & ~(size_t)255;
    return p;
  };
  c.h    = (float*)bump((size_t)C*PLANE*4);
  c.L    = (u16*)bump((size_t)C*PLANE*2);   // LN out / hop pong
  c.Q    = (u16*)bump((size_t)C*PLANE*2);
  c.Bp   = (u16*)bump((size_t)C*PLANE*2);   // k
  c.Cp   = (u16*)bump((size_t)C*PLANE*2);   // v
  c.T    = (u16*)bump((size_t)C*PLANE*2);   // v-hop pong / v3
  c.kvf  = (float*)bump((size_t)C*DD*DD*4);
  c.w2t  = (u16*)bump((size_t)C*2*DD*DD*2); // split pair
  c.ksum = (float*)bump((size_t)C*DD*4);
  c.rs   = (float*)bump((size_t)C*NN*4);
  c.off  = (int*)bump((size_t)BB*(NN+1)*4);
  c.cursor=(int*)bump((size_t)BB*(NN+1)*4);
  c.srcE = (int*)bump((size_t)NE*4);
  c.wt_gqkv = (u16*)bump((size_t)LL*2*768*256*2);
  c.wt_aqkv = (u16*)bump((size_t)LL*2*768*256*2);
  c.wt_gout = (u16*)bump((size_t)LL*2*256*256*2);
  c.wt_aout = (u16*)bump((size_t)LL*2*256*256*2);
  c.total = cur;
  return c;
}

extern "C" void kernel_launch(void* const* d_in, const int* in_sizes, int n_in,
                              void* d_out, int out_size, void* d_ws, size_t ws_size,
                              hipStream_t stream)
{
  const float* x        = (const float*)d_in[0];
  const int*   knn      = (const int*)d_in[1];
  const float* emb_w    = (const float*)d_in[2];
  const float* emb_b    = (const float*)d_in[3];
  const float* norm_g   = (const float*)d_in[4];
  const float* norm_b   = (const float*)d_in[5];
  const float* grf_qkv  = (const float*)d_in[6];
  const float* grf_outw = (const float*)d_in[7];
  const float* grf_outb = (const float*)d_in[8];
  const float* attn_qkv = (const float*)d_in[9];
  const float* attn_outw= (const float*)d_in[10];
  const float* attn_outb= (const float*)d_in[11];
  const float* head_w   = (const float*)d_in[12];
  const float* head_b   = (const float*)d_in[13];
  float* out = (float*)d_out;

  int C = 1;
  for(int cc=BB; cc>=1; cc>>=1){ if(carve(nullptr, cc).total <= ws_size){ C = cc; break; } }
  Carve ws = carve((char*)d_ws, C);

  // ---- weight prep (hi/lo fp16, transposed to [N][K]) ----
  k_prepw<<<dim3(768, LL), 256, 0, stream>>>(grf_qkv,  ws.wt_gqkv, 768);
  k_prepw<<<dim3(768, LL), 256, 0, stream>>>(attn_qkv, ws.wt_aqkv, 768);
  k_prepw<<<dim3(256, LL), 256, 0, stream>>>(grf_outw, ws.wt_gout, 256);
  k_prepw<<<dim3(256, LL), 256, 0, stream>>>(attn_outw,ws.wt_aout, 256);

  // ---- CSR build for all batches ----
  hipMemsetAsync(ws.off, 0, (size_t)BB*(NN+1)*sizeof(int), stream);
  k_count<<<dim3((NE+255)/256), 256, 0, stream>>>(knn, ws.off);
  k_scan<<<dim3(BB), 1024, 0, stream>>>(ws.off);
  hipMemcpyAsync(ws.cursor, ws.off, (size_t)BB*(NN+1)*sizeof(int), hipMemcpyDeviceToDevice, stream);
  k_fill<<<dim3((NE+255)/256), 256, 0, stream>>>(knn, ws.cursor, ws.srcE);

  const long PL = PLANE;
  for(int b0=0; b0<BB; b0+=C){
    const int* offB  = ws.off  + (long)b0*(NN+1);
    const int* srcB  = ws.srcE + (long)b0*NN*KK;

    k_embed<<<dim3(NN, C), 256, 0, stream>>>(x + (long)b0*NN*3, emb_w, emb_b, ws.h);

    for(int i=0; i<LL; i++){
      // ===== GRF sublayer =====
      k_ln<<<dim3(NN/4, C), 256, 0, stream>>>(ws.h, norm_g + (2*i)*DD, norm_b + (2*i)*DD, ws.L);
      k_mgemm<128,128,false,false,true><<<dim3(64, 6, C), 256, 0, stream>>>(
          ws.L, PL, 0, 256, 1,
          ws.wt_gqkv + (long)i*2*768*256, 0, (long)768*256,
          nullptr, 0, nullptr,
          ws.Q, ws.Bp, ws.Cp, PL, 0, 0, nullptr, 0);
      // hops: (Bp,Cp)->(L,T)->(Bp,Cp)-> final: v3 into T + fused rowdot
      k_spmm2<0><<<dim3(C, NN/8), 256, 0, stream>>>(ws.Bp, ws.Cp, offB, srcB, ws.L, ws.T, nullptr, nullptr);
      k_spmm2<0><<<dim3(C, NN/8), 256, 0, stream>>>(ws.L,  ws.T,  offB, srcB, ws.Bp, ws.Cp, nullptr, nullptr);
      k_spmm2<1><<<dim3(C, NN/8), 256, 0, stream>>>(ws.Bp, ws.Cp, offB, srcB, nullptr, ws.T, ws.Q, ws.rs);
      // h += (rs * v3) @ grf_outw + grf_outb
      k_mgemm<128,128,false,false,true><<<dim3(64, 2, C), 256, 0, stream>>>(
          ws.T, PL, 0, 256, 1,
          ws.wt_gout + (long)i*2*256*256, 0, (long)256*256,
          ws.rs, NN, grf_outb + (long)i*DD,
          nullptr, nullptr, nullptr, 0, 0, 0, ws.h, PL);

      // ===== linear attention sublayer =====
      k_ln<<<dim3(NN/4, C), 256, 0, stream>>>(ws.h, norm_g + (2*i+1)*DD, norm_b + (2*i+1)*DD, ws.L);
      k_mgemm<128,128,false,false,true><<<dim3(64, 6, C), 256, 0, stream>>>(
          ws.L, PL, 0, 256, 1,
          ws.wt_aqkv + (long)i*2*768*256, 0, (long)768*256,
          nullptr, 0, nullptr,
          ws.Q, ws.Bp, ws.Cp, PL, 3 /* relu+1e-6 on q,k */, 0, nullptr, 0);
      // kv + ksum straight from row-major Bp/Cp (no transposes)
      hipMemsetAsync(ws.kvf, 0, (size_t)C*DD*DD*sizeof(float), stream);
      hipMemsetAsync(ws.ksum, 0, (size_t)C*DD*sizeof(float), stream);
      k_ksum2<<<dim3(16, C), 256, 0, stream>>>(ws.Bp, ws.ksum);
      k_kv<<<dim3(4, 4, C*8), 256, 0, stream>>>(ws.Bp, ws.Cp, ws.kvf);
      // w2t[n][d] = sum_e WoutT[n][e](split) * kv[d][e]  -> split fp16 pair
      k_mgemm<64,64,true,true,false><<<dim3(4, 4, C), 256, 0, stream>>>(
          ws.wt_aout + (long)i*2*256*256, 0, (long)256*256, 256, 1,
          ws.kvf, (long)DD*DD, 0,
          nullptr, 0, nullptr,
          ws.w2t, nullptr, nullptr, (long)DD*DD, 0, (long)DD*DD,
          nullptr, 0);
      k_zcalc<<<dim3(NN/4, C), 256, 0, stream>>>(ws.Q, ws.ksum, ws.rs);
      // h += (z * q) @ w2 + attn_outb
      k_mgemm<128,128,false,false,true><<<dim3(64, 2, C), 256, 0, stream>>>(
          ws.Q, PL, 0, 256, 1,
          ws.w2t, 2L*DD*DD, (long)DD*DD,
          ws.rs, NN, attn_outb + (long)i*DD,
          nullptr, nullptr, nullptr, 0, 0, 0, ws.h, PL);
    }

    k_head<<<dim3(NN/4, C), 256, 0, stream>>>(ws.h, head_w, head_b, out + (long)b0*NN*3);
  }
}

// Round 14
// 2584.077 us; speedup vs baseline: 1.0622x; 1.0622x over previous
//
#include <hip/hip_runtime.h>

#define BB 8
#define NN 8192
#define KK 6
#define DD 256
#define LL 5
#define NE (BB*NN*KK)       // 393216
#define PLANE (NN*DD)       // 2097152 elems per batch
#define INV6 (1.0f/6.000001f)

typedef unsigned short u16;
typedef __attribute__((ext_vector_type(8))) _Float16 h8;
typedef __attribute__((ext_vector_type(8))) unsigned short us8;
typedef __attribute__((ext_vector_type(4))) float f32x4;

__device__ __forceinline__ u16 f2h(float f){
  union { _Float16 h; u16 u; } c; c.h = (_Float16)f; return c.u;
}
__device__ __forceinline__ float h2f(u16 u){
  union { _Float16 h; u16 u; } c; c.u = u; return (float)c.h;
}

// async global->LDS 16B copy: LDS dest must be wave-uniform base + lane*16
__device__ __forceinline__ void ldscp(const u16* g, u16* l){
  __builtin_amdgcn_global_load_lds(
      (const __attribute__((address_space(1))) void*)g,
      (__attribute__((address_space(3))) void*)l, 16, 0, 0);
}

// ---------------- CSR build ----------------
__global__ void k_count(const int* __restrict__ knn, int* __restrict__ off){
  int e = blockIdx.x*256 + threadIdx.x;
  if(e >= NE) return;
  int b = e / (NN*KK);
  int j = knn[e];
  atomicAdd(&off[b*(NN+1) + 1 + j], 1);
}

__global__ __launch_bounds__(1024) void k_scan(int* __restrict__ offAll){
  __shared__ int lds[1024];
  __shared__ int carry_s;
  int* off = offAll + blockIdx.x*(NN+1);
  const int len = NN+1;
  int t = threadIdx.x;
  if(t==0) carry_s = 0;
  __syncthreads();
  for(int base=0; base<len; base+=1024){
    int x = (base+t < len) ? off[base+t] : 0;
    lds[t] = x; __syncthreads();
    for(int s=1; s<1024; s<<=1){
      int v = (t>=s) ? lds[t-s] : 0;
      __syncthreads();
      lds[t] += v;
      __syncthreads();
    }
    int incl = lds[t];
    int carry = carry_s;
    __syncthreads();
    if(base+t < len) off[base+t] = incl + carry;
    if(t==1023) carry_s = carry + incl;
    __syncthreads();
  }
}

__global__ void k_fill(const int* __restrict__ knn, int* __restrict__ cursor, int* __restrict__ srcE){
  int e = blockIdx.x*256 + threadIdx.x;
  if(e >= NE) return;
  int b = e / (NN*KK);
  int n = (e % (NN*KK)) / KK;
  int j = knn[e];
  int pos = atomicAdd(&cursor[b*(NN+1) + j], 1);
  srcE[(long)b*NN*KK + pos] = n;
}

// ---- weight prep: W fp32 [L][256][N] -> Wt hi/lo fp16 [L][2][N][256] ----
__global__ __launch_bounds__(256) void k_prepw(const float* __restrict__ W, u16* __restrict__ Wt, int N){
  int n = blockIdx.x, l = blockIdx.y, k = threadIdx.x;
  float x = W[((long)l*256 + k)*N + n];
  u16 hb = f2h(x);
  Wt[(((long)l*2 + 0)*N + n)*256 + k] = hb;
  Wt[(((long)l*2 + 1)*N + n)*256 + k] = f2h(x - h2f(hb));
}

// ---------------- embed ----------------
__global__ __launch_bounds__(256) void k_embed(const float* __restrict__ x, const float* __restrict__ ew,
                        const float* __restrict__ eb, float* __restrict__ h){
  int g = blockIdx.x, z = blockIdx.y, d = threadIdx.x;
  const float* xp = x + ((long)z*NN + g)*3;
  h[(long)z*PLANE + (long)g*DD + d] = xp[0]*ew[0*DD+d] + xp[1]*ew[1*DD+d] + xp[2]*ew[2*DD+d] + eb[d];
}

// ---------------- layernorm fp32 -> fp16 single plane (layer-0 only) ----------------
__global__ __launch_bounds__(256) void k_ln(const float* __restrict__ h, const float* __restrict__ g,
                     const float* __restrict__ bia, u16* __restrict__ out){
  long z = blockIdx.y;
  int row = blockIdx.x*4 + (threadIdx.x >> 6);
  int lane = threadIdx.x & 63;
  const float4 x = *(const float4*)(h + z*PLANE + (long)row*DD + lane*4);
  float s  = x.x + x.y + x.z + x.w;
  float s2 = x.x*x.x + x.y*x.y + x.z*x.z + x.w*x.w;
  for(int o=1;o<64;o<<=1){ s += __shfl_xor(s,o); s2 += __shfl_xor(s2,o); }
  float m = s*(1.0f/256.0f);
  float var = s2*(1.0f/256.0f) - m*m;
  float r = rsqrtf(var + 1e-5f);
  const float4 gu = *(const float4*)(g + lane*4);
  const float4 bu = *(const float4*)(bia + lane*4);
  ushort4 o4;
  o4.x = f2h((x.x-m)*r*gu.x + bu.x);
  o4.y = f2h((x.y-m)*r*gu.y + bu.y);
  o4.z = f2h((x.z-m)*r*gu.z + bu.z);
  o4.w = f2h((x.w-m)*r*gu.w + bu.w);
  *(ushort4*)(out + z*PLANE + (long)row*DD + lane*4) = o4;
}

// ---------------- fp16 MFMA GEMM (qkv 128-tile sections + w2t/kv 64-tile legacy) ----------------
template<int BM,int BN,bool ASPLIT,bool BF32,bool BSPLIT>
__global__ __launch_bounds__(256) void k_mgemm(
    const u16* __restrict__ A, long aStride, long aLoOff, int K, int kSplit,
    const void* __restrict__ Bv, long bStride, long bLoOff,
    const float* __restrict__ rowscale, long rsStride,
    const float* __restrict__ bias,
    u16* __restrict__ o0, u16* __restrict__ o1, u16* __restrict__ o2,
    long oStride, int reluMask, long oLoOff,
    float* __restrict__ accOut, long hStride)
{
  constexpr int WM = BM/2, WN = BN/2, MT = WM/16, NT = WN/16;
  constexpr int STG = BM*32*(ASPLIT?2:1) + BN*32*(BSPLIT?2:1);
  constexpr int EPI = (BM==128) ? 32*132*2 : 0;
  constexpr int SM  = (STG > EPI) ? STG : EPI;
  __shared__ __align__(16) u16 smem[SM];
  u16* Ahi = smem;
  u16* Alo = smem + BM*32;
  u16* Bhi = smem + BM*32*(ASPLIT?2:1);
  u16* Blo = Bhi + BN*32;
  float* epi = (float*)smem;

  const int t = threadIdx.x;
  const int nz = blockIdx.z;
  const long z = nz / kSplit;
  const int chunk = nz % kSplit;
  const int kLen = K / kSplit, kLo = chunk * kLen;
  const int rowTile = blockIdx.x*BM, colTile = blockIdx.y*BN;
  const int l = t & 63, w = t >> 6;
  const int wr = w >> 1, wc = w & 1;
  const int lm = l & 15, kq = l >> 4;

  f32x4 acc[MT][NT];
  #pragma unroll
  for(int mt=0;mt<MT;mt++)
    #pragma unroll
    for(int nt=0;nt<NT;nt++) acc[mt][nt] = (f32x4){0.f,0.f,0.f,0.f};

  for(int k0=kLo; k0<kLo+kLen; k0+=32){
    __syncthreads();
    {
      constexpr int NCH = BM/64;
      #pragma unroll
      for(int li=0; li<NCH; li++){
        int f = li*256 + t;
        int row = f>>2, c = (f&3)*8;
        const u16* gp = A + z*aStride + (long)(rowTile+row)*K + k0 + c;
        ldscp(gp, &Ahi[f*8]);
        if constexpr (ASPLIT) ldscp(gp + aLoOff, &Alo[f*8]);
      }
    }
    if constexpr (BF32){
      constexpr int NCH = BN/64;
      #pragma unroll
      for(int li=0; li<NCH; li++){
        int f = li*256 + t;
        int row = f>>2, c = (f&3)*8;
        const float* src = (const float*)Bv + z*bStride + (long)(colTile+row)*K + k0 + c;
        float4 v0 = ((const float4*)src)[0], v1 = ((const float4*)src)[1];
        us8 hv;
        hv[0]=f2h(v0.x); hv[1]=f2h(v0.y); hv[2]=f2h(v0.z); hv[3]=f2h(v0.w);
        hv[4]=f2h(v1.x); hv[5]=f2h(v1.y); hv[6]=f2h(v1.z); hv[7]=f2h(v1.w);
        *(us8*)&Bhi[f*8] = hv;
      }
    } else {
      constexpr int NCH = BN/64;
      #pragma unroll
      for(int li=0; li<NCH; li++){
        int f = li*256 + t;
        int row = f>>2, c = (f&3)*8;
        const u16* gp = (const u16*)Bv + z*bStride + (long)(colTile+row)*K + k0 + c;
        ldscp(gp, &Bhi[f*8]);
        if constexpr (BSPLIT) ldscp(gp + bLoOff, &Blo[f*8]);
      }
    }
    __syncthreads();
    h8 ah[MT], al[MT], bh[NT], bl[NT];
    #pragma unroll
    for(int mt=0;mt<MT;mt++){
      int idx = (wr*WM + mt*16 + lm)*32 + kq*8;
      ah[mt] = *(const h8*)&Ahi[idx];
      if constexpr (ASPLIT) al[mt] = *(const h8*)&Alo[idx];
    }
    #pragma unroll
    for(int nt=0;nt<NT;nt++){
      int idx = (wc*WN + nt*16 + lm)*32 + kq*8;
      bh[nt] = *(const h8*)&Bhi[idx];
      if constexpr (BSPLIT) bl[nt] = *(const h8*)&Blo[idx];
    }
    #pragma unroll
    for(int mt=0;mt<MT;mt++)
      #pragma unroll
      for(int nt=0;nt<NT;nt++){
        acc[mt][nt] = __builtin_amdgcn_mfma_f32_16x16x32_f16(ah[mt], bh[nt], acc[mt][nt], 0, 0, 0);
        if constexpr (BSPLIT)
          acc[mt][nt] = __builtin_amdgcn_mfma_f32_16x16x32_f16(ah[mt], bl[nt], acc[mt][nt], 0, 0, 0);
        if constexpr (ASPLIT)
          acc[mt][nt] = __builtin_amdgcn_mfma_f32_16x16x32_f16(al[mt], bh[nt], acc[mt][nt], 0, 0, 0);
      }
  }

  if constexpr (BM == 128){
    const int sec = colTile >> 8;
    u16* osec = (sec==0) ? o0 : ((sec==1) ? o1 : o2);
    const bool relu = (reluMask >> sec) & 1;
    #pragma unroll
    for(int mt=0;mt<MT;mt++){
      __syncthreads();
      #pragma unroll
      for(int r=0;r<4;r++){
        int gm = rowTile + wr*64 + mt*16 + kq*4 + r;
        float sc = rowscale ? rowscale[z*rsStride + gm] : 1.0f;
        int rl = wr*16 + kq*4 + r;
        #pragma unroll
        for(int nt=0;nt<NT;nt++)
          epi[rl*132 + wc*64 + nt*16 + lm] = acc[mt][nt][r]*sc;
      }
      __syncthreads();
      #pragma unroll
      for(int ss=0;ss<2;ss++){
        int s = ss*256 + t;
        int rl = s >> 4, sc8 = (s & 15)*8;
        int gm2 = rowTile + (rl>>4)*64 + mt*16 + (rl & 15);
        float v[8];
        #pragma unroll
        for(int j=0;j<8;j++) v[j] = epi[rl*132 + sc8 + j];
        if(bias){
          const float* bp = bias + colTile + sc8;
          #pragma unroll
          for(int j=0;j<8;j++) v[j] += bp[j];
        }
        if(accOut){
          float* hp = accOut + z*hStride + (long)gm2*256 + colTile + sc8;
          float4 h0 = ((float4*)hp)[0], h1 = ((float4*)hp)[1];
          h0.x += v[0]; h0.y += v[1]; h0.z += v[2]; h0.w += v[3];
          h1.x += v[4]; h1.y += v[5]; h1.z += v[6]; h1.w += v[7];
          ((float4*)hp)[0] = h0; ((float4*)hp)[1] = h1;
        } else {
          us8 o8;
          #pragma unroll
          for(int j=0;j<8;j++){
            float vv = v[j];
            if(relu) vv = fmaxf(vv, 0.f) + 1e-6f;
            o8[j] = f2h(vv);
          }
          *(us8*)(osec + z*oStride + (long)gm2*256 + ((colTile + sc8) & 255)) = o8;
        }
      }
    }
  } else {
    #pragma unroll
    for(int mt=0;mt<MT;mt++){
      #pragma unroll
      for(int r=0;r<4;r++){
        int gm = rowTile + wr*WM + mt*16 + kq*4 + r;
        float sc = rowscale ? rowscale[z*rsStride + gm] : 1.0f;
        if(accOut){
          float* hp = accOut + z*hStride + (long)gm*256;
          if(kSplit > 1){
            #pragma unroll
            for(int nt=0;nt<NT;nt++){
              int gc = colTile + wc*WN + nt*16 + lm;
              atomicAdd(&hp[gc], acc[mt][nt][r]);
            }
          } else {
            #pragma unroll
            for(int nt=0;nt<NT;nt++){
              int gc = colTile + wc*WN + nt*16 + lm;
              hp[gc] += acc[mt][nt][r]*sc + (bias ? bias[gc] : 0.f);
            }
          }
        } else {
          #pragma unroll
          for(int nt=0;nt<NT;nt++){
            int gc = colTile + wc*WN + nt*16 + lm;
            int sec = gc >> 8;
            u16* o = (sec==0) ? o0 : ((sec==1) ? o1 : o2);
            float val = acc[mt][nt][r]*sc + (bias ? bias[gc] : 0.f);
            if((reluMask >> sec) & 1) val = fmaxf(val, 0.f) + 1e-6f;
            if(sec==0 && oLoOff){
              u16* oo = o0 + 2*z*oStride + (long)gm*256 + (gc & 255);
              u16 hb = f2h(val);
              oo[0] = hb;
              oo[oLoOff] = f2h(val - h2f(hb));
            } else {
              o[z*oStride + (long)gm*256 + (gc & 255)] = f2h(val);
            }
          }
        }
      }
    }
  }
}

// ---------------- fused out-projection: GEMM + h RMW + next LayerNorm ----------------
// BM=64, BN=256. A fp16 single, B fp16 hi/lo pair (+bLoOff, per-batch bStride).
// h[z][m][:] += acc*rowscale[m] + bias[:]; if lnG: L = LN(h_new) fp16.
// LN stats reduction mirrors k_ln EXACTLY (per-lane float4 partial, 64-lane
// butterfly) so the numeric trajectory matches R10 bit-for-bit.
__global__ __launch_bounds__(256) void k_fusedout(
    const u16* __restrict__ A, const u16* __restrict__ B, long bStride, long bLoOff,
    const float* __restrict__ rowscale, const float* __restrict__ bias,
    float* __restrict__ h,
    const float* __restrict__ lnG, const float* __restrict__ lnB,
    u16* __restrict__ Lout)
{
  constexpr int SMU = 64*32 + 2*256*32;      // 36,864 B staging; epi 32*260*4=33,280 B fits
  __shared__ __align__(16) u16 smem[SMU];
  u16* As = smem;
  u16* Bh = smem + 64*32;
  u16* Bl = Bh + 256*32;
  float* epi = (float*)smem;

  const int t = threadIdx.x;
  const long z = blockIdx.z;
  const int rowTile = blockIdx.x*64;
  const int l = t & 63, w = t >> 6;
  const int wr = w >> 1, wc = w & 1;
  const int lm = l & 15, kq = l >> 4;
  const u16* Ab = A + z*PLANE;
  const u16* Bb = B + z*bStride;

  f32x4 acc[2][8];
  #pragma unroll
  for(int mt=0;mt<2;mt++)
    #pragma unroll
    for(int nt=0;nt<8;nt++) acc[mt][nt] = (f32x4){0.f,0.f,0.f,0.f};

  for(int k0=0; k0<256; k0+=32){
    __syncthreads();
    { // A: 64x32 = one 16B chunk per thread
      ldscp(Ab + (long)(rowTile+(t>>2))*256 + k0 + (t&3)*8, &As[t*8]);
    }
    #pragma unroll
    for(int li=0; li<4; li++){ // B: 256x32 per buffer
      int f = li*256 + t;
      int row = f>>2, c = (f&3)*8;
      const u16* gp = Bb + (long)row*256 + k0 + c;
      ldscp(gp, &Bh[f*8]);
      ldscp(gp + bLoOff, &Bl[f*8]);
    }
    __syncthreads();
    h8 af[2], bh[8], bl[8];
    #pragma unroll
    for(int mt=0;mt<2;mt++)
      af[mt] = *(const h8*)&As[(wr*32 + mt*16 + lm)*32 + kq*8];
    #pragma unroll
    for(int nt=0;nt<8;nt++){
      int idx = (wc*128 + nt*16 + lm)*32 + kq*8;
      bh[nt] = *(const h8*)&Bh[idx];
      bl[nt] = *(const h8*)&Bl[idx];
    }
    #pragma unroll
    for(int mt=0;mt<2;mt++)
      #pragma unroll
      for(int nt=0;nt<8;nt++){
        acc[mt][nt] = __builtin_amdgcn_mfma_f32_16x16x32_f16(af[mt], bh[nt], acc[mt][nt], 0, 0, 0);
        acc[mt][nt] = __builtin_amdgcn_mfma_f32_16x16x32_f16(af[mt], bl[nt], acc[mt][nt], 0, 0, 0);
      }
  }

  // two phases of 32 rows; full 256 cols per row in LDS
  #pragma unroll
  for(int mt=0;mt<2;mt++){
    __syncthreads();
    #pragma unroll
    for(int r=0;r<4;r++){
      int rl = wr*16 + kq*4 + r;
      int gm = rowTile + wr*32 + mt*16 + kq*4 + r;
      float sc = rowscale ? rowscale[z*NN + gm] : 1.0f;
      #pragma unroll
      for(int nt=0;nt<8;nt++)
        epi[rl*260 + wc*128 + nt*16 + lm] = acc[mt][nt][r]*sc;
    }
    __syncthreads();
    // store phase: one 64-lane wave per row, float4 per lane (k_ln-identical)
    #pragma unroll
    for(int ss=0;ss<8;ss++){
      int s = ss*256 + t;
      int rl = s >> 6;               // 0..31 (uniform per wave)
      int c4 = (s & 63)*4;           // lane*4
      int gm = rowTile + (rl>>4)*32 + mt*16 + (rl & 15);
      float4 e = *(float4*)&epi[rl*260 + c4];
      float4 x;
      x.x = e.x + bias[c4+0];
      x.y = e.y + bias[c4+1];
      x.z = e.z + bias[c4+2];
      x.w = e.w + bias[c4+3];
      float* hp = h + z*PLANE + (long)gm*256 + c4;
      float4 h0 = *(float4*)hp;
      x.x += h0.x; x.y += h0.y; x.z += h0.z; x.w += h0.w;
      *(float4*)hp = x;
      if(lnG){
        float sA = x.x + x.y + x.z + x.w;
        float s2 = x.x*x.x + x.y*x.y + x.z*x.z + x.w*x.w;
        for(int o=1;o<64;o<<=1){ sA += __shfl_xor(sA,o); s2 += __shfl_xor(s2,o); }
        float m = sA*(1.0f/256.0f);
        float var = s2*(1.0f/256.0f) - m*m;
        float rr = rsqrtf(var + 1e-5f);
        const float4 gu = *(const float4*)(lnG + c4);
        const float4 bu = *(const float4*)(lnB + c4);
        ushort4 o4;
        o4.x = f2h((x.x-m)*rr*gu.x + bu.x);
        o4.y = f2h((x.y-m)*rr*gu.y + bu.y);
        o4.z = f2h((x.z-m)*rr*gu.z + bu.z);
        o4.w = f2h((x.w-m)*rr*gu.w + bu.w);
        *(ushort4*)(Lout + z*PLANE + (long)gm*256 + c4) = o4;
      }
    }
  }
}

// ------------- fused k+v spmm gather (fp16 planes, fp32 accum) -------------
template<int MODE>
__global__ __launch_bounds__(256) void k_spmm2(
    const u16* __restrict__ kin, const u16* __restrict__ vin,
    const int* __restrict__ offB, const int* __restrict__ srcB,
    u16* __restrict__ kout, u16* __restrict__ vout,
    const u16* __restrict__ q, float* __restrict__ rs){
  long z = blockIdx.x;
  const u16* kp = kin + z*PLANE;
  const u16* vp = vin + z*PLANE;
  const int* off = offB + z*(NN+1);
  const int* sE  = srcB + z*(long)NN*KK;
  int row = blockIdx.y*8 + (threadIdx.x >> 5);
  int l32 = threadIdx.x & 31;
  int d8 = l32*8;
  int s0 = off[row], s1 = off[row+1];
  float ak[8], av[8];
  #pragma unroll
  for(int j=0;j<8;j++){ ak[j]=0.f; av[j]=0.f; }
  int e = s0;
  for(; e+1 < s1; e += 2){
    int n0 = sE[e], n1 = sE[e+1];
    us8 k0 = *(const us8*)(kp + (long)n0*DD + d8);
    us8 k1 = *(const us8*)(kp + (long)n1*DD + d8);
    us8 v0 = *(const us8*)(vp + (long)n0*DD + d8);
    us8 v1 = *(const us8*)(vp + (long)n1*DD + d8);
    #pragma unroll
    for(int j=0;j<8;j++){
      ak[j] += h2f(k0[j]) + h2f(k1[j]);
      av[j] += h2f(v0[j]) + h2f(v1[j]);
    }
  }
  if(e < s1){
    int n0 = sE[e];
    us8 k0 = *(const us8*)(kp + (long)n0*DD + d8);
    us8 v0 = *(const us8*)(vp + (long)n0*DD + d8);
    #pragma unroll
    for(int j=0;j<8;j++){ ak[j] += h2f(k0[j]); av[j] += h2f(v0[j]); }
  }
  if constexpr (MODE == 0){
    us8 ok, ov;
    #pragma unroll
    for(int j=0;j<8;j++){ ok[j] = f2h(ak[j]*INV6); ov[j] = f2h(av[j]*INV6); }
    *(us8*)(kout + z*PLANE + (long)row*DD + d8) = ok;
    *(us8*)(vout + z*PLANE + (long)row*DD + d8) = ov;
  } else {
    us8 ov;
    #pragma unroll
    for(int j=0;j<8;j++) ov[j] = f2h(av[j]*INV6);
    *(us8*)(vout + z*PLANE + (long)row*DD + d8) = ov;
    us8 qv = *(const us8*)(q + z*PLANE + (long)row*DD + d8);
    float s = 0.f;
    #pragma unroll
    for(int j=0;j<8;j++) s += h2f(qv[j]) * ak[j];
    for(int o=1;o<32;o<<=1) s += __shfl_xor(s,o);
    if(l32==0) rs[z*NN + row] = s*INV6;
  }
}

// ---------------- z = 1/(q . ksum + 1e-6), q fp16 ----------------
__global__ __launch_bounds__(256) void k_zcalc(const u16* __restrict__ q, const float* __restrict__ ksum,
                        float* __restrict__ rs){
  long z = blockIdx.y;
  int row = blockIdx.x*4 + (threadIdx.x >> 6);
  int lane = threadIdx.x & 63;
  ushort4 qv = *(const ushort4*)(q + z*PLANE + (long)row*DD + lane*4);
  const float4 c = *(const float4*)(ksum + z*DD + lane*4);
  float s = h2f(qv.x)*c.x + h2f(qv.y)*c.y + h2f(qv.z)*c.z + h2f(qv.w)*c.w;
  for(int o=1;o<64;o<<=1) s += __shfl_xor(s,o);
  if(lane==0) rs[z*NN + row] = 1.0f / (s + 1e-6f);
}

// ---- dual transpose fp16 [8192][256] -> [256][8192]: two tensors per launch ----
__global__ __launch_bounds__(256) void k_transp2(
    const u16* __restrict__ in0, u16* __restrict__ out0,
    const u16* __restrict__ in1, u16* __restrict__ out1){
  __shared__ u16 tile[64][72];
  int zz = blockIdx.z;
  long z = zz >> 1;
  const u16* ip = ((zz & 1) ? in1 : in0) + z*PLANE;
  u16* op = ((zz & 1) ? out1 : out0) + z*PLANE;
  int r0 = blockIdx.x*64, c0 = blockIdx.y*64;
  int t = threadIdx.x;
  {
    int r = t>>2, cg = (t&3)*16;
    *(us8*)&tile[r][cg]   = *(const us8*)(ip + (long)(r0+r)*DD + c0 + cg);
    *(us8*)&tile[r][cg+8] = *(const us8*)(ip + (long)(r0+r)*DD + c0 + cg + 8);
  }
  __syncthreads();
  {
    int c = t>>2, rg = t&3;
    us8 a, b;
    #pragma unroll
    for(int j=0;j<8;j++){ a[j] = tile[rg*16+j][c]; b[j] = tile[rg*16+8+j][c]; }
    u16* dst = op + (long)(c0+c)*NN + r0 + rg*16;
    *(us8*)dst = a; *(us8*)(dst+8) = b;
  }
}

// ---- ksum[d] = sum_n kT[d][n], kT fp16 [256][8192] ----
__global__ __launch_bounds__(256) void k_ksum(const u16* __restrict__ kT, float* __restrict__ ksum){
  long z = blockIdx.y;
  int d = blockIdx.x;
  const u16* p = kT + z*PLANE + (long)d*NN;
  float s = 0.f;
  for(int i=threadIdx.x*8; i<NN; i+=2048){
    us8 a = *(const us8*)(p+i);
    #pragma unroll
    for(int j=0;j<8;j++) s += h2f(a[j]);
  }
  for(int o=1;o<64;o<<=1) s += __shfl_xor(s,o);
  __shared__ float ws4[4];
  int w = threadIdx.x >> 6;
  if((threadIdx.x & 63)==0) ws4[w] = s;
  __syncthreads();
  if(threadIdx.x==0) ksum[z*DD + d] = ws4[0]+ws4[1]+ws4[2]+ws4[3];
}

// ---------------- head ----------------
__global__ __launch_bounds__(256) void k_head(const float* __restrict__ h, const float* __restrict__ hw,
                       const float* __restrict__ hb, float* __restrict__ out){
  long z = blockIdx.y;
  int row = blockIdx.x*4 + (threadIdx.x >> 6);
  int lane = threadIdx.x & 63;
  const float4 x = *(const float4*)(h + z*PLANE + (long)row*DD + lane*4);
  int d0 = lane*4;
  float a0 = x.x*hw[(d0+0)*3+0] + x.y*hw[(d0+1)*3+0] + x.z*hw[(d0+2)*3+0] + x.w*hw[(d0+3)*3+0];
  float a1 = x.x*hw[(d0+0)*3+1] + x.y*hw[(d0+1)*3+1] + x.z*hw[(d0+2)*3+1] + x.w*hw[(d0+3)*3+1];
  float a2 = x.x*hw[(d0+0)*3+2] + x.y*hw[(d0+1)*3+2] + x.z*hw[(d0+2)*3+2] + x.w*hw[(d0+3)*3+2];
  for(int o=1;o<64;o<<=1){
    a0 += __shfl_xor(a0,o); a1 += __shfl_xor(a1,o); a2 += __shfl_xor(a2,o);
  }
  if(lane==0){
    float* op = out + (z*NN + row)*3;
    op[0] = a0 + hb[0];
    op[1] = a1 + hb[1];
    op[2] = a2 + hb[2];
  }
}

struct Carve {
  float *h; u16 *L,*Q,*Bp,*Cp,*T;
  float *kvf; u16 *w2t;
  float *ksum,*rs;
  int *off,*cursor,*srcE;
  u16 *wt_gqkv,*wt_aqkv,*wt_gout,*wt_aout;
  size_t total;
};

static Carve carve(char* base, int C){
  Carve c;
  size_t cur = 0;
  auto bump = [&](size_t bytes)->char*{
    char* p = base ? base + cur : (char*)0;
    cur += (bytes + 255) & ~(size_t)255;
    return p;
  };
  c.h    = (float*)bump((size_t)C*PLANE*4);
  c.L    = (u16*)bump((size_t)C*PLANE*2);   // LN out / hop pong / kT
  c.Q    = (u16*)bump((size_t)C*PLANE*2);
  c.Bp   = (u16*)bump((size_t)C*PLANE*2);   // k
  c.Cp   = (u16*)bump((size_t)C*PLANE*2);   // v
  c.T    = (u16*)bump((size_t)C*PLANE*2);   // v-hop pong / v3 / vT
  c.kvf  = (float*)bump((size_t)C*DD*DD*4);
  c.w2t  = (u16*)bump((size_t)C*2*DD*DD*2); // split pair
  c.ksum = (float*)bump((size_t)C*DD*4);
  c.rs   = (float*)bump((size_t)C*NN*4);
  c.off  = (int*)bump((size_t)BB*(NN+1)*4);
  c.cursor=(int*)bump((size_t)BB*(NN+1)*4);
  c.srcE = (int*)bump((size_t)NE*4);
  c.wt_gqkv = (u16*)bump((size_t)LL*2*768*256*2);
  c.wt_aqkv = (u16*)bump((size_t)LL*2*768*256*2);
  c.wt_gout = (u16*)bump((size_t)LL*2*256*256*2);
  c.wt_aout = (u16*)bump((size_t)LL*2*256*256*2);
  c.total = cur;
  return c;
}

extern "C" void kernel_launch(void* const* d_in, const int* in_sizes, int n_in,
                              void* d_out, int out_size, void* d_ws, size_t ws_size,
                              hipStream_t stream)
{
  const float* x        = (const float*)d_in[0];
  const int*   knn      = (const int*)d_in[1];
  const float* emb_w    = (const float*)d_in[2];
  const float* emb_b    = (const float*)d_in[3];
  const float* norm_g   = (const float*)d_in[4];
  const float* norm_b   = (const float*)d_in[5];
  const float* grf_qkv  = (const float*)d_in[6];
  const float* grf_outw = (const float*)d_in[7];
  const float* grf_outb = (const float*)d_in[8];
  const float* attn_qkv = (const float*)d_in[9];
  const float* attn_outw= (const float*)d_in[10];
  const float* attn_outb= (const float*)d_in[11];
  const float* head_w   = (const float*)d_in[12];
  const float* head_b   = (const float*)d_in[13];
  float* out = (float*)d_out;

  int C = 1;
  for(int cc=BB; cc>=1; cc>>=1){ if(carve(nullptr, cc).total <= ws_size){ C = cc; break; } }
  Carve ws = carve((char*)d_ws, C);

  // ---- weight prep (hi/lo fp16, transposed to [N][K]) ----
  k_prepw<<<dim3(768, LL), 256, 0, stream>>>(grf_qkv,  ws.wt_gqkv, 768);
  k_prepw<<<dim3(768, LL), 256, 0, stream>>>(attn_qkv, ws.wt_aqkv, 768);
  k_prepw<<<dim3(256, LL), 256, 0, stream>>>(grf_outw, ws.wt_gout, 256);
  k_prepw<<<dim3(256, LL), 256, 0, stream>>>(attn_outw,ws.wt_aout, 256);

  // ---- CSR build for all batches ----
  hipMemsetAsync(ws.off, 0, (size_t)BB*(NN+1)*sizeof(int), stream);
  k_count<<<dim3((NE+255)/256), 256, 0, stream>>>(knn, ws.off);
  k_scan<<<dim3(BB), 1024, 0, stream>>>(ws.off);
  hipMemcpyAsync(ws.cursor, ws.off, (size_t)BB*(NN+1)*sizeof(int), hipMemcpyDeviceToDevice, stream);
  k_fill<<<dim3((NE+255)/256), 256, 0, stream>>>(knn, ws.cursor, ws.srcE);

  const long PL = PLANE;
  for(int b0=0; b0<BB; b0+=C){
    const int* offB  = ws.off  + (long)b0*(NN+1);
    const int* srcB  = ws.srcE + (long)b0*NN*KK;

    k_embed<<<dim3(NN, C), 256, 0, stream>>>(x + (long)b0*NN*3, emb_w, emb_b, ws.h);
    k_ln<<<dim3(NN/4, C), 256, 0, stream>>>(ws.h, norm_g, norm_b, ws.L);

    for(int i=0; i<LL; i++){
      // ===== GRF sublayer =====
      k_mgemm<128,128,false,false,true><<<dim3(64, 6, C), 256, 0, stream>>>(
          ws.L, PL, 0, 256, 1,
          ws.wt_gqkv + (long)i*2*768*256, 0, (long)768*256,
          nullptr, 0, nullptr,
          ws.Q, ws.Bp, ws.Cp, PL, 0, 0, nullptr, 0);
      // hops: (Bp,Cp)->(L,T)->(Bp,Cp)-> final: v3 into T + fused rowdot
      k_spmm2<0><<<dim3(C, NN/8), 256, 0, stream>>>(ws.Bp, ws.Cp, offB, srcB, ws.L, ws.T, nullptr, nullptr);
      k_spmm2<0><<<dim3(C, NN/8), 256, 0, stream>>>(ws.L,  ws.T,  offB, srcB, ws.Bp, ws.Cp, nullptr, nullptr);
      k_spmm2<1><<<dim3(C, NN/8), 256, 0, stream>>>(ws.Bp, ws.Cp, offB, srcB, nullptr, ws.T, ws.Q, ws.rs);
      // h += (rs*v3) @ grf_outw + grf_outb ; fused LN -> L (attn LN, norm 2i+1)
      k_fusedout<<<dim3(NN/64, 1, C), 256, 0, stream>>>(
          ws.T, ws.wt_gout + (long)i*2*256*256, 0, (long)256*256,
          ws.rs, grf_outb + (long)i*DD, ws.h,
          norm_g + (2*i+1)*DD, norm_b + (2*i+1)*DD, ws.L);

      // ===== linear attention sublayer =====
      k_mgemm<128,128,false,false,true><<<dim3(64, 6, C), 256, 0, stream>>>(
          ws.L, PL, 0, 256, 1,
          ws.wt_aqkv + (long)i*2*768*256, 0, (long)768*256,
          nullptr, 0, nullptr,
          ws.Q, ws.Bp, ws.Cp, PL, 3 /* relu+1e-6 on q,k */, 0, nullptr, 0);
      // kT = Bp^T -> L (LN dead after qkv) ; vT = Cp^T -> T (one dispatch)
      k_transp2<<<dim3(NN/64, DD/64, 2*C), 256, 0, stream>>>(ws.Bp, ws.L, ws.Cp, ws.T);
      k_ksum<<<dim3(DD, C), 256, 0, stream>>>(ws.L, ws.ksum);
      // kv[d][e] = sum_n kT[d][n] * vT[e][n]  (split-K=8, atomic fp32)
      hipMemsetAsync(ws.kvf, 0, (size_t)C*DD*DD*sizeof(float), stream);
      k_mgemm<64,64,false,false,false><<<dim3(4, 4, C*8), 256, 0, stream>>>(
          ws.L, PL, 0, NN, 8,
          ws.T, PL, 0,
          nullptr, 0, nullptr,
          nullptr, nullptr, nullptr, 0, 0, 0, ws.kvf, (long)DD*DD);
      // w2t[n][d] = sum_e WoutT[n][e](split) * kv[d][e]  -> split fp16 pair
      k_mgemm<64,64,true,true,false><<<dim3(4, 4, C), 256, 0, stream>>>(
          ws.wt_aout + (long)i*2*256*256, 0, (long)256*256, 256, 1,
          ws.kvf, (long)DD*DD, 0,
          nullptr, 0, nullptr,
          ws.w2t, nullptr, nullptr, (long)DD*DD, 0, (long)DD*DD,
          nullptr, 0);
      k_zcalc<<<dim3(NN/4, C), 256, 0, stream>>>(ws.Q, ws.ksum, ws.rs);
      // h += (z*q) @ w2 + attn_outb ; fused LN -> L (next GRF LN) unless last layer
      const float* g2 = (i==LL-1) ? nullptr : norm_g + (2*i+2)*DD;
      const float* b2 = (i==LL-1) ? nullptr : norm_b + (2*i+2)*DD;
      k_fusedout<<<dim3(NN/64, 1, C), 256, 0, stream>>>(
          ws.Q, ws.w2t, 2L*DD*DD, (long)DD*DD,
          ws.rs, attn_outb + (long)i*DD, ws.h,
          g2, b2, ws.L);
    }

    k_head<<<dim3(NN/4, C), 256, 0, stream>>>(ws.h, head_w, head_b, out + (long)b0*NN*3);
  }
}